// Round 3
// baseline (691.580 us; speedup 1.0000x reference)
//
#include <hip/hip_runtime.h>
#include <hip/hip_bf16.h>
#include <stdint.h>
#include <stddef.h>

#define B_ 4
#define N_ 1024
#define C_ 384
#define H_ 6
#define D_ 64
#define TC_ 1152          // 3*C
#define BHND_ 1572864     // B*H*N*D
#define BHNN_ 25165824    // B*H*N*N
#define SCALE 0.125f

// ---------------- Threefry-2x32 (matches jax._src.prng) ----------------
#define TFR(x0,x1,r) { x0 += x1; x1 = ((x1)<<(r))|((x1)>>(32-(r))); x1 ^= x0; }

__host__ __device__ __forceinline__ void tf2x32(uint32_t k0, uint32_t k1,
                                                uint32_t& x0, uint32_t& x1){
  uint32_t k2 = k0 ^ k1 ^ 0x1BD11BDAu;
  x0 += k0; x1 += k1;
  TFR(x0,x1,13) TFR(x0,x1,15) TFR(x0,x1,26) TFR(x0,x1,6)
  x0 += k1; x1 += k2 + 1u;
  TFR(x0,x1,17) TFR(x0,x1,29) TFR(x0,x1,16) TFR(x0,x1,24)
  x0 += k2; x1 += k0 + 2u;
  TFR(x0,x1,13) TFR(x0,x1,15) TFR(x0,x1,26) TFR(x0,x1,6)
  x0 += k0; x1 += k1 + 3u;
  TFR(x0,x1,17) TFR(x0,x1,29) TFR(x0,x1,16) TFR(x0,x1,24)
  x0 += k1; x1 += k2 + 4u;
  TFR(x0,x1,13) TFR(x0,x1,15) TFR(x0,x1,26) TFR(x0,x1,6)
  x0 += k2; x1 += k0 + 5u;
}

// partitionable threefry random bits: bits(j) = w0 ^ w1 of block(key, (0, j))
__device__ __forceinline__ float gumbel_p(uint32_t k0, uint32_t k1, uint32_t j){
  uint32_t x0 = 0u, x1 = j;
  tf2x32(k0, k1, x0, x1);
  uint32_t bits = x0 ^ x1;
  float f = __uint_as_float((bits >> 9) | 0x3F800000u) - 1.0f;  // [0,1)
  f = fmaxf(f, 1.1754943508222875e-38f);                        // minval=tiny
  return -logf(-logf(f));
}

// ---------------- Kernel A: qkv = x @ qkv_w + b, scatter to q/k/v (B,H,N,D) f32
__global__ __launch_bounds__(256) void k_qkv(const float* __restrict__ x,
                                             const float* __restrict__ w,
                                             const float* __restrict__ bias,
                                             float* __restrict__ qT){
  __shared__ float As[16][68];   // [k][m]
  __shared__ float Bs[16][68];   // [k][n]
  const int t  = threadIdx.x;
  const int tx = t & 15, ty = t >> 4;
  const int m0 = blockIdx.x * 64, n0 = blockIdx.y * 64;
  float c[4][4] = {};
  for (int k0 = 0; k0 < C_; k0 += 16){
    #pragma unroll
    for (int i = 0; i < 4; i++){
      int idx = t + 256*i;               // 1024 A elems: 64m x 16k
      int m = idx >> 4, k = idx & 15;
      As[k][m] = x[(size_t)(m0+m)*C_ + k0 + k];
      int n = idx & 63, k2 = idx >> 6;   // 1024 B elems: 16k x 64n
      Bs[k2][n] = w[(size_t)(k0+k2)*TC_ + n0 + n];
    }
    __syncthreads();
    #pragma unroll
    for (int k = 0; k < 16; k++){
      float av[4], bv[4];
      #pragma unroll
      for (int i = 0; i < 4; i++) av[i] = As[k][ty*4+i];
      #pragma unroll
      for (int j = 0; j < 4; j++) bv[j] = Bs[k][tx*4+j];
      #pragma unroll
      for (int i = 0; i < 4; i++)
        #pragma unroll
        for (int j = 0; j < 4; j++) c[i][j] += av[i]*bv[j];
    }
    __syncthreads();
  }
  #pragma unroll
  for (int i = 0; i < 4; i++){
    int mg = m0 + ty*4 + i;
    int bb = mg >> 10, nn = mg & 1023;
    #pragma unroll
    for (int j = 0; j < 4; j++){
      int jg = n0 + tx*4 + j;
      int t3 = jg / C_;
      int rem = jg - t3*C_;
      int h = rem >> 6, d = rem & 63;
      float val = c[i][j] + bias[jg];
      qT[(size_t)t3*BHND_ + ((size_t)(bb*H_ + h)*N_ + nn)*D_ + d] = val;
    }
  }
}

// ---------------- Kernel B: scores[bh][n][m] = sum_d q[n,d]*k[m,d] -> f32 (attn region)
__global__ __launch_bounds__(256) void k_scores(const float* __restrict__ qT,
                                                float* __restrict__ qk){
  __shared__ float qs[64][65];   // [d][n]
  __shared__ float ks[64][65];   // [d][m]
  const int bh = blockIdx.z;
  const float* q = qT + (size_t)bh * N_ * D_;
  const float* k = qT + (size_t)BHND_ + (size_t)bh * N_ * D_;
  const int n0 = blockIdx.y * 64, m0 = blockIdx.x * 64;
  const int t = threadIdx.x;
  const int tx = t & 15, ty = t >> 4;
  #pragma unroll
  for (int i = 0; i < 16; i++){
    int idx = t + 256*i;               // 4096 elems: 64 rows x 64 d
    int d = idx & 63, r = idx >> 6;
    qs[d][r] = q[(size_t)(n0+r)*D_ + d];
    ks[d][r] = k[(size_t)(m0+r)*D_ + d];
  }
  __syncthreads();
  float c[4][4] = {};
  #pragma unroll 8
  for (int d = 0; d < 64; d++){
    float av[4], bv[4];
    #pragma unroll
    for (int i = 0; i < 4; i++) av[i] = qs[d][ty*4+i];
    #pragma unroll
    for (int j = 0; j < 4; j++) bv[j] = ks[d][tx*4+j];
    #pragma unroll
    for (int i = 0; i < 4; i++)
      #pragma unroll
      for (int j = 0; j < 4; j++) c[i][j] += av[i]*bv[j];
  }
  float* outp = qk + (size_t)bh * N_ * N_;
  #pragma unroll
  for (int i = 0; i < 4; i++)
    #pragma unroll
    for (int j = 0; j < 4; j++)
      outp[(size_t)(n0+ty*4+i)*N_ + m0+tx*4+j] = c[i][j];
}

// ---------------- Kernel C: per-row (b,h,n) softmax stats over m
__global__ __launch_bounds__(256) void k_stats(const float* __restrict__ qk,
                                               float* __restrict__ stats){
  const int row = blockIdx.x;            // 24576 rows
  const float* p = qk + (size_t)row * N_;
  const int t = threadIdx.x, lid = t & 63, wid = t >> 6;
  float v[4];
  #pragma unroll
  for (int i = 0; i < 4; i++) v[i] = p[t + 256*i];
  float mx = fmaxf(fmaxf(v[0], v[1]), fmaxf(v[2], v[3]));
  #pragma unroll
  for (int off = 32; off > 0; off >>= 1) mx = fmaxf(mx, __shfl_down(mx, off));
  __shared__ float redm[4], reds[4];
  if (lid == 0) redm[wid] = mx;
  __syncthreads();
  mx = fmaxf(fmaxf(redm[0], redm[1]), fmaxf(redm[2], redm[3]));
  float msc = mx * SCALE;
  float s = 0.f;
  #pragma unroll
  for (int i = 0; i < 4; i++) s += expf(v[i]*SCALE - msc);
  #pragma unroll
  for (int off = 32; off > 0; off >>= 1) s += __shfl_down(s, off);
  if (lid == 0) reds[wid] = s;
  __syncthreads();
  if (t == 0){
    float S = reds[0] + reds[1] + reds[2] + reds[3];
    stats[(size_t)row*2 + 0] = msc;
    stats[(size_t)row*2 + 1] = 1.0f / S;
  }
}

// ---------------- Kernel D: softmax (in-place) + conv + tanh + gumbel mask bits
__global__ __launch_bounds__(256) void k_fuse(float* __restrict__ attn,    // in: scores, out: attn_mean
                                              const float* __restrict__ stats,
                                              const float* __restrict__ cw,
                                              const float* __restrict__ cb,
                                              float* __restrict__ u_out,
                                              unsigned long long* __restrict__ mbits,
                                              uint32_t g0k0, uint32_t g0k1,
                                              uint32_t g1k0, uint32_t g1k1){
  const int flat = blockIdx.x * 256 + threadIdx.x;   // over B*N*N
  const int m = flat & (N_-1);
  const int n = (flat >> 10) & (N_-1);
  const int bb = flat >> 20;
  const int lane = threadIdx.x & 63;
  float qv[H_];
  #pragma unroll
  for (int h = 0; h < H_; h++){
    size_t idx = ((size_t)(bb*H_ + h) << 20) | ((size_t)n << 10) | (size_t)m;
    qv[h] = attn[idx];
    int row = (bb*H_ + h)*N_ + n;
    float M = stats[(size_t)row*2 + 0];
    float invS = stats[(size_t)row*2 + 1];
    attn[idx] = expf(qv[h]*SCALE - M) * invS;
  }
  #pragma unroll
  for (int o = 0; o < H_; o++){
    float up = cb[o];
    #pragma unroll
    for (int h = 0; h < H_; h++) up += cw[o*H_ + h] * qv[h];
    float uu = 0.5f * (tanhf(up) + 1.0f);     // log(exp(u)) == u
    uint32_t j = ((uint32_t)(bb*H_ + o) << 20) | ((uint32_t)n << 10) | (uint32_t)m;
    float gg0 = gumbel_p(g0k0, g0k1, j);
    float gg1 = gumbel_p(g1k0, g1k1, j);
    int hard = ((1.0f - uu) + gg1) > (uu + gg0);
    u_out[(size_t)j] = uu;
    unsigned long long bal = __ballot(hard);   // m is 64-aligned per wave
    if (lane == 0) mbits[(size_t)j >> 6] = bal;
  }
}

// ---------------- Kernel E: tmp[b,n,h,d] = sum_m (attn*mask)[bh,n,m] * v[bh,m,d]
__global__ __launch_bounds__(256) void k_av(const float* __restrict__ attn,
                                            const unsigned long long* __restrict__ mbits,
                                            const float* __restrict__ vT,
                                            float* __restrict__ tmp){
  __shared__ float as_[32][65];   // [mk][n]
  __shared__ float vs[32][65];    // [mk][d]
  const int bh = blockIdx.z;
  const int bb = bh / H_, h = bh - bb*H_;
  const float* A = attn + (size_t)bh * N_ * N_;
  const float* V = vT + (size_t)bh * N_ * D_;
  const int n0 = blockIdx.x * 64;
  const int t = threadIdx.x, tx = t & 15, ty = t >> 4;
  float c[4][4] = {};
  for (int m0 = 0; m0 < N_; m0 += 32){
    #pragma unroll
    for (int i = 0; i < 8; i++){
      int idx = t + 256*i;                 // 2048: 64n x 32mk
      int mk = idx & 31, nr = idx >> 5;
      int mg = m0 + mk;
      size_t e = ((size_t)bh << 20) | ((size_t)(n0+nr) << 10) | (size_t)mg;
      float a = A[(size_t)(n0+nr)*N_ + mg];
      unsigned long long wbits = mbits[e >> 6];
      as_[mk][nr] = ((wbits >> (mg & 63)) & 1ull) ? a : 0.0f;
      int d = idx & 63, mv = idx >> 6;     // 2048: 32mk x 64d
      vs[mv][d] = V[(size_t)(m0+mv)*D_ + d];
    }
    __syncthreads();
    #pragma unroll 8
    for (int mk = 0; mk < 32; mk++){
      float av[4], bv[4];
      #pragma unroll
      for (int i = 0; i < 4; i++) av[i] = as_[mk][ty*4+i];
      #pragma unroll
      for (int j = 0; j < 4; j++) bv[j] = vs[mk][tx*4+j];
      #pragma unroll
      for (int i = 0; i < 4; i++)
        #pragma unroll
        for (int j = 0; j < 4; j++) c[i][j] += av[i]*bv[j];
    }
    __syncthreads();
  }
  #pragma unroll
  for (int i = 0; i < 4; i++)
    #pragma unroll
    for (int j = 0; j < 4; j++)
      tmp[((size_t)(bb*N_ + n0+ty*4+i))*C_ + h*D_ + tx*4 + j] = c[i][j];
}

// ---------------- Kernel F: out = tmp @ proj_w + proj_b (f32 out)
__global__ __launch_bounds__(256) void k_proj(const float* __restrict__ A,
                                              const float* __restrict__ w,
                                              const float* __restrict__ bias,
                                              float* __restrict__ out){
  __shared__ float As[16][68];
  __shared__ float Bs[16][68];
  const int t = threadIdx.x, tx = t & 15, ty = t >> 4;
  const int m0 = blockIdx.x * 64, n0 = blockIdx.y * 64;
  float c[4][4] = {};
  for (int k0 = 0; k0 < C_; k0 += 16){
    #pragma unroll
    for (int i = 0; i < 4; i++){
      int idx = t + 256*i;
      int m = idx >> 4, k = idx & 15;
      As[k][m] = A[(size_t)(m0+m)*C_ + k0 + k];
      int n = idx & 63, k2 = idx >> 6;
      Bs[k2][n] = w[(size_t)(k0+k2)*C_ + n0 + n];
    }
    __syncthreads();
    #pragma unroll
    for (int k = 0; k < 16; k++){
      float av[4], bv[4];
      #pragma unroll
      for (int i = 0; i < 4; i++) av[i] = As[k][ty*4+i];
      #pragma unroll
      for (int j = 0; j < 4; j++) bv[j] = Bs[k][tx*4+j];
      #pragma unroll
      for (int i = 0; i < 4; i++)
        #pragma unroll
        for (int j = 0; j < 4; j++) c[i][j] += av[i]*bv[j];
    }
    __syncthreads();
  }
  #pragma unroll
  for (int i = 0; i < 4; i++)
    #pragma unroll
    for (int j = 0; j < 4; j++)
      out[(size_t)(m0+ty*4+i)*C_ + n0+tx*4+j] = c[i][j] + bias[n0+tx*4+j];
}

extern "C" void kernel_launch(void* const* d_in, const int* in_sizes, int n_in,
                              void* d_out, int out_size, void* d_ws, size_t ws_size,
                              hipStream_t stream) {
  const float* x      = (const float*)d_in[0];
  const float* qkv_w  = (const float*)d_in[1];
  const float* qkv_b  = (const float*)d_in[2];
  const float* proj_w = (const float*)d_in[3];
  const float* proj_b = (const float*)d_in[4];
  const float* conv_w = (const float*)d_in[5];
  const float* conv_b = (const float*)d_in[6];

  float* out      = (float*)d_out;                      // B*N*C
  float* attn_out = out + (size_t)B_*N_*C_;             // B*H*N*N (scores then attn)
  float* u_out    = attn_out + (size_t)BHNN_;           // B*H*N*N

  // workspace layout (28.5 MB total)
  char* ws = (char*)d_ws;
  float* qT   = (float*)ws;                             // 3*BHND f32 = 18,874,368 B
  float* stats= (float*)(ws + 18874368);                // 24576*2 f32 = 196,608 B
  unsigned long long* mbits = (unsigned long long*)(ws + 19070976); // BHNN/8 = 3,145,728 B
  float* tmp  = (float*)(ws + 22216704);                // B*N*C f32 = 6,291,456 B

  // derived gumbel keys: fold_in(key(42)=(0,42), 0) and (.., 1)
  uint32_t g0k0, g0k1, g1k0, g1k1;
  { uint32_t a = 0u, b = 0u; tf2x32(0u, 42u, a, b); g0k0 = a; g0k1 = b; }
  { uint32_t a = 0u, b = 1u; tf2x32(0u, 42u, a, b); g1k0 = a; g1k1 = b; }

  dim3 blk(256);
  k_qkv   <<<dim3(64, 18),      blk, 0, stream>>>(x, qkv_w, qkv_b, qT);
  k_scores<<<dim3(16, 16, 24),  blk, 0, stream>>>(qT, attn_out);
  k_stats <<<dim3(24576),       blk, 0, stream>>>(attn_out, stats);
  k_fuse  <<<dim3(16384),       blk, 0, stream>>>(attn_out, stats, conv_w, conv_b,
                                                  u_out, mbits,
                                                  g0k0, g0k1, g1k0, g1k1);
  k_av    <<<dim3(16, 1, 24),   blk, 0, stream>>>(attn_out, mbits,
                                                  qT + 2*(size_t)BHND_, tmp);
  k_proj  <<<dim3(64, 6),       blk, 0, stream>>>(tmp, proj_w, proj_b, out);
}

// Round 4
// 661.641 us; speedup vs baseline: 1.0452x; 1.0452x over previous
//
#include <hip/hip_runtime.h>
#include <hip/hip_bf16.h>
#include <stdint.h>
#include <stddef.h>

#define B_ 4
#define N_ 1024
#define C_ 384
#define H_ 6
#define D_ 64
#define TC_ 1152          // 3*C
#define BHND_ 1572864     // B*H*N*D
#define BHNN_ 25165824    // B*H*N*N
#define SCALE 0.125f

// ---------------- Threefry-2x32 (matches jax._src.prng) ----------------
#define TFR(x0,x1,r) { x0 += x1; x1 = ((x1)<<(r))|((x1)>>(32-(r))); x1 ^= x0; }

__host__ __device__ __forceinline__ void tf2x32(uint32_t k0, uint32_t k1,
                                                uint32_t& x0, uint32_t& x1){
  uint32_t k2 = k0 ^ k1 ^ 0x1BD11BDAu;
  x0 += k0; x1 += k1;
  TFR(x0,x1,13) TFR(x0,x1,15) TFR(x0,x1,26) TFR(x0,x1,6)
  x0 += k1; x1 += k2 + 1u;
  TFR(x0,x1,17) TFR(x0,x1,29) TFR(x0,x1,16) TFR(x0,x1,24)
  x0 += k2; x1 += k0 + 2u;
  TFR(x0,x1,13) TFR(x0,x1,15) TFR(x0,x1,26) TFR(x0,x1,6)
  x0 += k0; x1 += k1 + 3u;
  TFR(x0,x1,17) TFR(x0,x1,29) TFR(x0,x1,16) TFR(x0,x1,24)
  x0 += k1; x1 += k2 + 4u;
  TFR(x0,x1,13) TFR(x0,x1,15) TFR(x0,x1,26) TFR(x0,x1,6)
  x0 += k2; x1 += k0 + 5u;
}

// partitionable threefry random bits: bits(j) = w0 ^ w1 of block(key, (0, j))
__device__ __forceinline__ float gumbel_p(uint32_t k0, uint32_t k1, uint32_t j){
  uint32_t x0 = 0u, x1 = j;
  tf2x32(k0, k1, x0, x1);
  uint32_t bits = x0 ^ x1;
  float f = __uint_as_float((bits >> 9) | 0x3F800000u) - 1.0f;  // [0,1)
  f = fmaxf(f, 1.1754943508222875e-38f);                        // minval=tiny
  return -logf(-logf(f));
}

// ---------------- Kernel Z: zero the AV accumulator (ws is poisoned each launch)
__global__ __launch_bounds__(256) void k_zero(float4* __restrict__ p){
  p[blockIdx.x * 256 + threadIdx.x] = make_float4(0.f, 0.f, 0.f, 0.f);
}

// ---------------- Kernel A: qkv = x @ qkv_w + b, scatter to q/k/v (B,H,N,D) f32
__global__ __launch_bounds__(256) void k_qkv(const float* __restrict__ x,
                                             const float* __restrict__ w,
                                             const float* __restrict__ bias,
                                             float* __restrict__ qT){
  __shared__ float As[16][68];   // [k][m]
  __shared__ float Bs[16][68];   // [k][n]
  const int t  = threadIdx.x;
  const int tx = t & 15, ty = t >> 4;
  const int m0 = blockIdx.x * 64, n0 = blockIdx.y * 64;
  float c[4][4] = {};
  for (int k0 = 0; k0 < C_; k0 += 16){
    #pragma unroll
    for (int i = 0; i < 4; i++){
      int idx = t + 256*i;               // 1024 A elems: 64m x 16k
      int m = idx >> 4, k = idx & 15;
      As[k][m] = x[(size_t)(m0+m)*C_ + k0 + k];
      int n = idx & 63, k2 = idx >> 6;   // 1024 B elems: 16k x 64n
      Bs[k2][n] = w[(size_t)(k0+k2)*TC_ + n0 + n];
    }
    __syncthreads();
    #pragma unroll
    for (int k = 0; k < 16; k++){
      float av[4], bv[4];
      #pragma unroll
      for (int i = 0; i < 4; i++) av[i] = As[k][ty*4+i];
      #pragma unroll
      for (int j = 0; j < 4; j++) bv[j] = Bs[k][tx*4+j];
      #pragma unroll
      for (int i = 0; i < 4; i++)
        #pragma unroll
        for (int j = 0; j < 4; j++) c[i][j] += av[i]*bv[j];
    }
    __syncthreads();
  }
  #pragma unroll
  for (int i = 0; i < 4; i++){
    int mg = m0 + ty*4 + i;
    int bb = mg >> 10, nn = mg & 1023;
    #pragma unroll
    for (int j = 0; j < 4; j++){
      int jg = n0 + tx*4 + j;
      int t3 = jg / C_;
      int rem = jg - t3*C_;
      int h = rem >> 6, d = rem & 63;
      float val = c[i][j] + bias[jg];
      qT[(size_t)t3*BHND_ + ((size_t)(bb*H_ + h)*N_ + nn)*D_ + d] = val;
    }
  }
}

// ---------------- Kernel B: scores[bh][n][m] = sum_d q[n,d]*k[m,d] -> f32 (attn region)
__global__ __launch_bounds__(256) void k_scores(const float* __restrict__ qT,
                                                float* __restrict__ qk){
  __shared__ float qs[64][65];   // [d][n]
  __shared__ float ks[64][65];   // [d][m]
  const int bh = blockIdx.z;
  const float* q = qT + (size_t)bh * N_ * D_;
  const float* k = qT + (size_t)BHND_ + (size_t)bh * N_ * D_;
  const int n0 = blockIdx.y * 64, m0 = blockIdx.x * 64;
  const int t = threadIdx.x;
  const int tx = t & 15, ty = t >> 4;
  #pragma unroll
  for (int i = 0; i < 16; i++){
    int idx = t + 256*i;               // 4096 elems: 64 rows x 64 d
    int d = idx & 63, r = idx >> 6;
    qs[d][r] = q[(size_t)(n0+r)*D_ + d];
    ks[d][r] = k[(size_t)(m0+r)*D_ + d];
  }
  __syncthreads();
  float c[4][4] = {};
  #pragma unroll 8
  for (int d = 0; d < 64; d++){
    float av[4], bv[4];
    #pragma unroll
    for (int i = 0; i < 4; i++) av[i] = qs[d][ty*4+i];
    #pragma unroll
    for (int j = 0; j < 4; j++) bv[j] = ks[d][tx*4+j];
    #pragma unroll
    for (int i = 0; i < 4; i++)
      #pragma unroll
      for (int j = 0; j < 4; j++) c[i][j] += av[i]*bv[j];
  }
  float* outp = qk + (size_t)bh * N_ * N_;
  #pragma unroll
  for (int i = 0; i < 4; i++)
    #pragma unroll
    for (int j = 0; j < 4; j++)
      outp[(size_t)(n0+ty*4+i)*N_ + m0+tx*4+j] = c[i][j];
}

// ---------------- Kernel C: per-row (b,h,n) softmax stats over m
__global__ __launch_bounds__(256) void k_stats(const float* __restrict__ qk,
                                               float* __restrict__ stats){
  const int row = blockIdx.x;            // 24576 rows
  const float* p = qk + (size_t)row * N_;
  const int t = threadIdx.x, lid = t & 63, wid = t >> 6;
  float v[4];
  #pragma unroll
  for (int i = 0; i < 4; i++) v[i] = p[t + 256*i];
  float mx = fmaxf(fmaxf(v[0], v[1]), fmaxf(v[2], v[3]));
  #pragma unroll
  for (int off = 32; off > 0; off >>= 1) mx = fmaxf(mx, __shfl_down(mx, off));
  __shared__ float redm[4], reds[4];
  if (lid == 0) redm[wid] = mx;
  __syncthreads();
  mx = fmaxf(fmaxf(redm[0], redm[1]), fmaxf(redm[2], redm[3]));
  float msc = mx * SCALE;
  float s = 0.f;
  #pragma unroll
  for (int i = 0; i < 4; i++) s += expf(v[i]*SCALE - msc);
  #pragma unroll
  for (int off = 32; off > 0; off >>= 1) s += __shfl_down(s, off);
  if (lid == 0) reds[wid] = s;
  __syncthreads();
  if (t == 0){
    float S = reds[0] + reds[1] + reds[2] + reds[3];
    stats[(size_t)row*2 + 0] = msc;
    stats[(size_t)row*2 + 1] = 1.0f / S;
  }
}

// ---------------- Kernel D: softmax (in-place) + conv + tanh + gumbel mask bits
__global__ __launch_bounds__(256) void k_fuse(float* __restrict__ attn,    // in: scores, out: attn_mean
                                              const float* __restrict__ stats,
                                              const float* __restrict__ cw,
                                              const float* __restrict__ cb,
                                              float* __restrict__ u_out,
                                              unsigned long long* __restrict__ mbits,
                                              uint32_t g0k0, uint32_t g0k1,
                                              uint32_t g1k0, uint32_t g1k1){
  const int flat = blockIdx.x * 256 + threadIdx.x;   // over B*N*N
  const int m = flat & (N_-1);
  const int n = (flat >> 10) & (N_-1);
  const int bb = flat >> 20;
  const int lane = threadIdx.x & 63;
  float qv[H_];
  #pragma unroll
  for (int h = 0; h < H_; h++){
    size_t idx = ((size_t)(bb*H_ + h) << 20) | ((size_t)n << 10) | (size_t)m;
    qv[h] = attn[idx];
    int row = (bb*H_ + h)*N_ + n;
    float M = stats[(size_t)row*2 + 0];
    float invS = stats[(size_t)row*2 + 1];
    attn[idx] = expf(qv[h]*SCALE - M) * invS;
  }
  #pragma unroll
  for (int o = 0; o < H_; o++){
    float up = cb[o];
    #pragma unroll
    for (int h = 0; h < H_; h++) up += cw[o*H_ + h] * qv[h];
    float uu = 0.5f * (tanhf(up) + 1.0f);     // log(exp(u)) == u
    uint32_t j = ((uint32_t)(bb*H_ + o) << 20) | ((uint32_t)n << 10) | (uint32_t)m;
    float gg0 = gumbel_p(g0k0, g0k1, j);
    float gg1 = gumbel_p(g1k0, g1k1, j);
    int hard = ((1.0f - uu) + gg1) > (uu + gg0);
    u_out[(size_t)j] = uu;
    unsigned long long bal = __ballot(hard);   // m is 64-aligned per wave
    if (lane == 0) mbits[(size_t)j >> 6] = bal;
  }
}

// ---------------- Kernel E: tmp[b,n,h,d] += sum_{m in chunk} (attn*mask)[bh,n,m]*v[bh,m,d]
// grid (16 n-tiles, 4 m-chunks, 24 bh); partials combined via atomicAdd.
__global__ __launch_bounds__(256) void k_av(const float* __restrict__ attn,
                                            const unsigned long long* __restrict__ mbits,
                                            const float* __restrict__ vT,
                                            float* __restrict__ tmp){
  __shared__ float as_[32][65];   // [mk][n]
  __shared__ float vs[32][65];    // [mk][d]
  const int bh = blockIdx.z;
  const int bb = bh / H_, h = bh - bb*H_;
  const float* A = attn + (size_t)bh * N_ * N_;
  const float* V = vT + (size_t)bh * N_ * D_;
  const int n0 = blockIdx.x * 64;
  const int mbase = blockIdx.y * 256;
  const int t = threadIdx.x, tx = t & 15, ty = t >> 4;
  float c[4][4] = {};
  for (int m0 = mbase; m0 < mbase + 256; m0 += 32){
    #pragma unroll
    for (int i = 0; i < 8; i++){
      int idx = t + 256*i;                 // 2048: 64n x 32mk
      int mk = idx & 31, nr = idx >> 5;
      int mg = m0 + mk;
      size_t e = ((size_t)bh << 20) | ((size_t)(n0+nr) << 10) | (size_t)mg;
      float a = A[(size_t)(n0+nr)*N_ + mg];
      unsigned long long wbits = mbits[e >> 6];
      as_[mk][nr] = ((wbits >> (mg & 63)) & 1ull) ? a : 0.0f;
      int d = idx & 63, mv = idx >> 6;     // 2048: 32mk x 64d
      vs[mv][d] = V[(size_t)(m0+mv)*D_ + d];
    }
    __syncthreads();
    #pragma unroll 8
    for (int mk = 0; mk < 32; mk++){
      float av[4], bv[4];
      #pragma unroll
      for (int i = 0; i < 4; i++) av[i] = as_[mk][ty*4+i];
      #pragma unroll
      for (int j = 0; j < 4; j++) bv[j] = vs[mk][tx*4+j];
      #pragma unroll
      for (int i = 0; i < 4; i++)
        #pragma unroll
        for (int j = 0; j < 4; j++) c[i][j] += av[i]*bv[j];
    }
    __syncthreads();
  }
  #pragma unroll
  for (int i = 0; i < 4; i++)
    #pragma unroll
    for (int j = 0; j < 4; j++)
      atomicAdd(&tmp[((size_t)(bb*N_ + n0+ty*4+i))*C_ + h*D_ + tx*4 + j], c[i][j]);
}

// ---------------- Kernel F: out = tmp @ proj_w + proj_b (f32 out), 32x64 tiles
__global__ __launch_bounds__(256) void k_proj(const float* __restrict__ A,
                                              const float* __restrict__ w,
                                              const float* __restrict__ bias,
                                              float* __restrict__ out){
  __shared__ float As[16][36];   // [k][m] 32 rows
  __shared__ float Bs[16][68];   // [k][n] 64 cols
  const int t = threadIdx.x, tx = t & 15, ty = t >> 4;
  const int m0 = blockIdx.x * 32, n0 = blockIdx.y * 64;
  float c[2][4] = {};
  for (int k0 = 0; k0 < C_; k0 += 16){
    {
      int idx = t;                        // 512 A elems: 32m x 16k (2/thread)
      int m = idx >> 4, k = idx & 15;
      As[k][m] = A[(size_t)(m0+m)*C_ + k0 + k];
      idx = t + 256;
      m = idx >> 4; k = idx & 15;
      As[k][m] = A[(size_t)(m0+m)*C_ + k0 + k];
    }
    #pragma unroll
    for (int i = 0; i < 4; i++){
      int idx = t + 256*i;                // 1024 B elems: 16k x 64n
      int n = idx & 63, k2 = idx >> 6;
      Bs[k2][n] = w[(size_t)(k0+k2)*C_ + n0 + n];
    }
    __syncthreads();
    #pragma unroll
    for (int k = 0; k < 16; k++){
      float av[2], bv[4];
      #pragma unroll
      for (int i = 0; i < 2; i++) av[i] = As[k][ty*2+i];
      #pragma unroll
      for (int j = 0; j < 4; j++) bv[j] = Bs[k][tx*4+j];
      #pragma unroll
      for (int i = 0; i < 2; i++)
        #pragma unroll
        for (int j = 0; j < 4; j++) c[i][j] += av[i]*bv[j];
    }
    __syncthreads();
  }
  #pragma unroll
  for (int i = 0; i < 2; i++)
    #pragma unroll
    for (int j = 0; j < 4; j++)
      out[(size_t)(m0+ty*2+i)*C_ + n0+tx*4+j] = c[i][j] + bias[n0+tx*4+j];
}

extern "C" void kernel_launch(void* const* d_in, const int* in_sizes, int n_in,
                              void* d_out, int out_size, void* d_ws, size_t ws_size,
                              hipStream_t stream) {
  const float* x      = (const float*)d_in[0];
  const float* qkv_w  = (const float*)d_in[1];
  const float* qkv_b  = (const float*)d_in[2];
  const float* proj_w = (const float*)d_in[3];
  const float* proj_b = (const float*)d_in[4];
  const float* conv_w = (const float*)d_in[5];
  const float* conv_b = (const float*)d_in[6];

  float* out      = (float*)d_out;                      // B*N*C
  float* attn_out = out + (size_t)B_*N_*C_;             // B*H*N*N (scores then attn)
  float* u_out    = attn_out + (size_t)BHNN_;           // B*H*N*N

  // workspace layout (28.5 MB total)
  char* ws = (char*)d_ws;
  float* qT   = (float*)ws;                             // 3*BHND f32 = 18,874,368 B
  float* stats= (float*)(ws + 18874368);                // 24576*2 f32 = 196,608 B
  unsigned long long* mbits = (unsigned long long*)(ws + 19070976); // BHNN/8 = 3,145,728 B
  float* tmp  = (float*)(ws + 22216704);                // B*N*C f32 = 6,291,456 B

  // derived gumbel keys: fold_in(key(42)=(0,42), 0) and (.., 1)
  uint32_t g0k0, g0k1, g1k0, g1k1;
  { uint32_t a = 0u, b = 0u; tf2x32(0u, 42u, a, b); g0k0 = a; g0k1 = b; }
  { uint32_t a = 0u, b = 1u; tf2x32(0u, 42u, a, b); g1k0 = a; g1k1 = b; }

  dim3 blk(256);
  k_qkv   <<<dim3(64, 18),      blk, 0, stream>>>(x, qkv_w, qkv_b, qT);
  k_zero  <<<dim3(1536),        blk, 0, stream>>>((float4*)tmp);   // 6.3MB = 1536*256*16B
  k_scores<<<dim3(16, 16, 24),  blk, 0, stream>>>(qT, attn_out);
  k_stats <<<dim3(24576),       blk, 0, stream>>>(attn_out, stats);
  k_fuse  <<<dim3(16384),       blk, 0, stream>>>(attn_out, stats, conv_w, conv_b,
                                                  u_out, mbits,
                                                  g0k0, g0k1, g1k0, g1k1);
  k_av    <<<dim3(16, 4, 24),   blk, 0, stream>>>(attn_out, mbits,
                                                  qT + 2*(size_t)BHND_, tmp);
  k_proj  <<<dim3(128, 6),      blk, 0, stream>>>(tmp, proj_w, proj_b, out);
}

// Round 5
// 550.249 us; speedup vs baseline: 1.2568x; 1.2024x over previous
//
#include <hip/hip_runtime.h>
#include <hip/hip_bf16.h>
#include <stdint.h>
#include <stddef.h>

#define B_ 4
#define N_ 1024
#define C_ 384
#define H_ 6
#define D_ 64
#define TC_ 1152          // 3*C
#define BHNN_ 25165824    // B*H*N*N
#define SCALE 0.125f

typedef __hip_bfloat16 bf16;
typedef __attribute__((ext_vector_type(4))) float f32x4;
typedef __attribute__((ext_vector_type(8))) short short8;

__device__ __forceinline__ short f2bs(float x){
  bf16 b = __float2bfloat16(x);
  return *reinterpret_cast<short*>(&b);
}

// ---------------- Threefry-2x32 (matches jax._src.prng) ----------------
#define TFR(x0,x1,r) { x0 += x1; x1 = ((x1)<<(r))|((x1)>>(32-(r))); x1 ^= x0; }

__host__ __device__ __forceinline__ void tf2x32(uint32_t k0, uint32_t k1,
                                                uint32_t& x0, uint32_t& x1){
  uint32_t k2 = k0 ^ k1 ^ 0x1BD11BDAu;
  x0 += k0; x1 += k1;
  TFR(x0,x1,13) TFR(x0,x1,15) TFR(x0,x1,26) TFR(x0,x1,6)
  x0 += k1; x1 += k2 + 1u;
  TFR(x0,x1,17) TFR(x0,x1,29) TFR(x0,x1,16) TFR(x0,x1,24)
  x0 += k2; x1 += k0 + 2u;
  TFR(x0,x1,13) TFR(x0,x1,15) TFR(x0,x1,26) TFR(x0,x1,6)
  x0 += k0; x1 += k1 + 3u;
  TFR(x0,x1,17) TFR(x0,x1,29) TFR(x0,x1,16) TFR(x0,x1,24)
  x0 += k1; x1 += k2 + 4u;
  TFR(x0,x1,13) TFR(x0,x1,15) TFR(x0,x1,26) TFR(x0,x1,6)
  x0 += k2; x1 += k0 + 5u;
}

// partitionable threefry random bits: bits(j) = w0 ^ w1 of block(key, (0, j))
__device__ __forceinline__ float gumbel_p(uint32_t k0, uint32_t k1, uint32_t j){
  uint32_t x0 = 0u, x1 = j;
  tf2x32(k0, k1, x0, x1);
  uint32_t bits = x0 ^ x1;
  float f = __uint_as_float((bits >> 9) | 0x3F800000u) - 1.0f;  // [0,1)
  f = fmaxf(f, 1.1754943508222875e-38f);                        // minval=tiny
  return -logf(-logf(f));
}

// ---------------- Kernel A: qkv = x @ qkv_w + b -> qb, kb (B,H,N,D bf16), vT (B,H,D,N bf16)
__global__ __launch_bounds__(256) void k_qkv(const float* __restrict__ x,
                                             const float* __restrict__ w,
                                             const float* __restrict__ bias,
                                             bf16* __restrict__ qb,
                                             bf16* __restrict__ kb,
                                             bf16* __restrict__ vTb){
  __shared__ float As[16][68];   // [k][m]
  __shared__ float Bs[16][68];   // [k][n]
  const int t  = threadIdx.x;
  const int tx = t & 15, ty = t >> 4;
  const int m0 = blockIdx.x * 64, n0 = blockIdx.y * 64;
  float c[4][4] = {};
  for (int k0 = 0; k0 < C_; k0 += 16){
    #pragma unroll
    for (int i = 0; i < 4; i++){
      int idx = t + 256*i;               // 1024 A elems: 64m x 16k
      int m = idx >> 4, k = idx & 15;
      As[k][m] = x[(size_t)(m0+m)*C_ + k0 + k];
      int n = idx & 63, k2 = idx >> 6;   // 1024 B elems: 16k x 64n
      Bs[k2][n] = w[(size_t)(k0+k2)*TC_ + n0 + n];
    }
    __syncthreads();
    #pragma unroll
    for (int k = 0; k < 16; k++){
      float av[4], bv[4];
      #pragma unroll
      for (int i = 0; i < 4; i++) av[i] = As[k][ty*4+i];
      #pragma unroll
      for (int j = 0; j < 4; j++) bv[j] = Bs[k][tx*4+j];
      #pragma unroll
      for (int i = 0; i < 4; i++)
        #pragma unroll
        for (int j = 0; j < 4; j++) c[i][j] += av[i]*bv[j];
    }
    __syncthreads();
  }
  #pragma unroll
  for (int i = 0; i < 4; i++){
    int mg = m0 + ty*4 + i;
    int bb = mg >> 10, nn = mg & 1023;
    #pragma unroll
    for (int j = 0; j < 4; j++){
      int jg = n0 + tx*4 + j;
      int t3 = jg / C_;
      int rem = jg - t3*C_;
      int h = rem >> 6, d = rem & 63;
      bf16 val = __float2bfloat16(c[i][j] + bias[jg]);
      if (t3 == 0)      qb[((size_t)(bb*H_ + h)*N_ + nn)*D_ + d] = val;
      else if (t3 == 1) kb[((size_t)(bb*H_ + h)*N_ + nn)*D_ + d] = val;
      else              vTb[((size_t)(bb*H_ + h)*D_ + d)*N_ + nn] = val;
    }
  }
}

// ---------------- Kernel B (MFMA): scores[bh][n][m] = sum_d q[n,d]*k[m,d] -> f32 (attn region)
// one 16x16 tile per wave; A/B frags loaded straight from global (16B per lane)
__global__ __launch_bounds__(256) void k_scores(const short* __restrict__ qb,
                                                const short* __restrict__ kb,
                                                float* __restrict__ qk){
  const int gw = blockIdx.x * 4 + (threadIdx.x >> 6);
  const int lane = threadIdx.x & 63;
  const int mt = gw & 63, nt = (gw >> 6) & 63, bh = gw >> 12;
  const int lo = lane & 15, quad = lane >> 4;
  const short* qrow = qb + ((size_t)bh*N_ + nt*16 + lo)*D_ + quad*8;
  const short* krow = kb + ((size_t)bh*N_ + mt*16 + lo)*D_ + quad*8;
  short8 a0 = *(const short8*)qrow;
  short8 b0 = *(const short8*)krow;
  short8 a1 = *(const short8*)(qrow + 32);
  short8 b1 = *(const short8*)(krow + 32);
  f32x4 acc = {0.f, 0.f, 0.f, 0.f};
  acc = __builtin_amdgcn_mfma_f32_16x16x32_bf16(a0, b0, acc, 0, 0, 0);
  acc = __builtin_amdgcn_mfma_f32_16x16x32_bf16(a1, b1, acc, 0, 0, 0);
  float* o = qk + (size_t)bh*N_*N_ + (size_t)(nt*16)*N_ + mt*16;
  #pragma unroll
  for (int r = 0; r < 4; r++)
    o[(size_t)(quad*4 + r)*N_ + lo] = acc[r];   // row=(lane>>4)*4+reg, col=lane&15
}

// ---------------- Kernel C: per-row (b,h,n) softmax stats over m
__global__ __launch_bounds__(256) void k_stats(const float* __restrict__ qk,
                                               float* __restrict__ stats){
  const int row = blockIdx.x;            // 24576 rows
  const float* p = qk + (size_t)row * N_;
  const int t = threadIdx.x, lid = t & 63, wid = t >> 6;
  float v[4];
  #pragma unroll
  for (int i = 0; i < 4; i++) v[i] = p[t + 256*i];
  float mx = fmaxf(fmaxf(v[0], v[1]), fmaxf(v[2], v[3]));
  #pragma unroll
  for (int off = 32; off > 0; off >>= 1) mx = fmaxf(mx, __shfl_down(mx, off));
  __shared__ float redm[4], reds[4];
  if (lid == 0) redm[wid] = mx;
  __syncthreads();
  mx = fmaxf(fmaxf(redm[0], redm[1]), fmaxf(redm[2], redm[3]));
  float msc = mx * SCALE;
  float s = 0.f;
  #pragma unroll
  for (int i = 0; i < 4; i++) s += expf(v[i]*SCALE - msc);
  #pragma unroll
  for (int off = 32; off > 0; off >>= 1) s += __shfl_down(s, off);
  if (lid == 0) reds[wid] = s;
  __syncthreads();
  if (t == 0){
    float S = reds[0] + reds[1] + reds[2] + reds[3];
    stats[(size_t)row*2 + 0] = msc;
    stats[(size_t)row*2 + 1] = 1.0f / S;
  }
}

// ---------------- Kernel D: softmax (in-place) + conv + tanh + gumbel mask bits
__global__ __launch_bounds__(256) void k_fuse(float* __restrict__ attn,    // in: scores, out: attn_mean
                                              const float* __restrict__ stats,
                                              const float* __restrict__ cw,
                                              const float* __restrict__ cb,
                                              float* __restrict__ u_out,
                                              unsigned long long* __restrict__ mbits,
                                              uint32_t g0k0, uint32_t g0k1,
                                              uint32_t g1k0, uint32_t g1k1){
  const int flat = blockIdx.x * 256 + threadIdx.x;   // over B*N*N
  const int m = flat & (N_-1);
  const int n = (flat >> 10) & (N_-1);
  const int bb = flat >> 20;
  const int lane = threadIdx.x & 63;
  float qv[H_];
  #pragma unroll
  for (int h = 0; h < H_; h++){
    size_t idx = ((size_t)(bb*H_ + h) << 20) | ((size_t)n << 10) | (size_t)m;
    qv[h] = attn[idx];
    int row = (bb*H_ + h)*N_ + n;
    float M = stats[(size_t)row*2 + 0];
    float invS = stats[(size_t)row*2 + 1];
    attn[idx] = expf(qv[h]*SCALE - M) * invS;
  }
  #pragma unroll
  for (int o = 0; o < H_; o++){
    float up = cb[o];
    #pragma unroll
    for (int h = 0; h < H_; h++) up += cw[o*H_ + h] * qv[h];
    float uu = 0.5f * (tanhf(up) + 1.0f);     // log(exp(u)) == u
    uint32_t j = ((uint32_t)(bb*H_ + o) << 20) | ((uint32_t)n << 10) | (uint32_t)m;
    float gg0 = gumbel_p(g0k0, g0k1, j);
    float gg1 = gumbel_p(g1k0, g1k1, j);
    int hard = ((1.0f - uu) + gg1) > (uu + gg0);
    u_out[(size_t)j] = uu;
    unsigned long long bal = __ballot(hard);   // m is 64-aligned per wave
    if (lane == 0) mbits[(size_t)j >> 6] = bal;
  }
}

// ---------------- Kernel E (MFMA): tmp[b,n,h,d] = sum_m (attn*mask)[bh,n,m] * v[bh,m,d]
// one 16(n)x16(d) tile per wave; A built in-reg from f32 attn + mask bits; B from vT bf16
__global__ __launch_bounds__(256) void k_av(const float* __restrict__ attn,
                                            const unsigned long long* __restrict__ mbits,
                                            const short* __restrict__ vTb,
                                            float* __restrict__ tmp){
  const int gw = blockIdx.x * 4 + (threadIdx.x >> 6);
  const int lane = threadIdx.x & 63;
  const int dt = gw & 3, nt = (gw >> 2) & 63, bh = gw >> 8;
  const int bb = bh / H_, h = bh - bb*H_;
  const int lo = lane & 15, quad = lane >> 4;
  const int row = nt*16 + lo;                       // n
  const float* arow = attn + ((size_t)bh*N_ + row)*N_ + quad*8;
  const unsigned long long* mrow = mbits + (((size_t)bh*N_ + row)*N_ >> 6);
  const short* vrow = vTb + ((size_t)bh*D_ + dt*16 + lo)*N_ + quad*8;
  f32x4 acc = {0.f, 0.f, 0.f, 0.f};
  for (int m0 = 0; m0 < N_; m0 += 32){
    f32x4 av0 = *(const f32x4*)(arow + m0);
    f32x4 av1 = *(const f32x4*)(arow + m0 + 4);
    unsigned long long wb = mrow[(m0 + quad*8) >> 6];
    int base = (m0 + quad*8) & 63;
    float vals[8] = {av0[0], av0[1], av0[2], av0[3], av1[0], av1[1], av1[2], av1[3]};
    short8 a;
    #pragma unroll
    for (int j = 0; j < 8; j++)
      a[j] = f2bs(((wb >> (base + j)) & 1ull) ? vals[j] : 0.0f);
    short8 b = *(const short8*)(vrow + m0);
    acc = __builtin_amdgcn_mfma_f32_16x16x32_bf16(a, b, acc, 0, 0, 0);
  }
  float* o = tmp + ((size_t)(bb*N_) + nt*16)*C_ + h*D_ + dt*16;
  #pragma unroll
  for (int r = 0; r < 4; r++)
    o[(size_t)(quad*4 + r)*C_ + lo] = acc[r];
}

// ---------------- Kernel F: out = tmp @ proj_w + proj_b (f32 out), 32x64 tiles
__global__ __launch_bounds__(256) void k_proj(const float* __restrict__ A,
                                              const float* __restrict__ w,
                                              const float* __restrict__ bias,
                                              float* __restrict__ out){
  __shared__ float As[16][36];   // [k][m] 32 rows
  __shared__ float Bs[16][68];   // [k][n] 64 cols
  const int t = threadIdx.x, tx = t & 15, ty = t >> 4;
  const int m0 = blockIdx.x * 32, n0 = blockIdx.y * 64;
  float c[2][4] = {};
  for (int k0 = 0; k0 < C_; k0 += 16){
    {
      int idx = t;                        // 512 A elems: 32m x 16k (2/thread)
      int m = idx >> 4, k = idx & 15;
      As[k][m] = A[(size_t)(m0+m)*C_ + k0 + k];
      idx = t + 256;
      m = idx >> 4; k = idx & 15;
      As[k][m] = A[(size_t)(m0+m)*C_ + k0 + k];
    }
    #pragma unroll
    for (int i = 0; i < 4; i++){
      int idx = t + 256*i;                // 1024 B elems: 16k x 64n
      int n = idx & 63, k2 = idx >> 6;
      Bs[k2][n] = w[(size_t)(k0+k2)*C_ + n0 + n];
    }
    __syncthreads();
    #pragma unroll
    for (int k = 0; k < 16; k++){
      float av[2], bv[4];
      #pragma unroll
      for (int i = 0; i < 2; i++) av[i] = As[k][ty*2+i];
      #pragma unroll
      for (int j = 0; j < 4; j++) bv[j] = Bs[k][tx*4+j];
      #pragma unroll
      for (int i = 0; i < 2; i++)
        #pragma unroll
        for (int j = 0; j < 4; j++) c[i][j] += av[i]*bv[j];
    }
    __syncthreads();
  }
  #pragma unroll
  for (int i = 0; i < 2; i++)
    #pragma unroll
    for (int j = 0; j < 4; j++)
      out[(size_t)(m0+ty*2+i)*C_ + n0+tx*4+j] = c[i][j] + bias[n0+tx*4+j];
}

extern "C" void kernel_launch(void* const* d_in, const int* in_sizes, int n_in,
                              void* d_out, int out_size, void* d_ws, size_t ws_size,
                              hipStream_t stream) {
  const float* x      = (const float*)d_in[0];
  const float* qkv_w  = (const float*)d_in[1];
  const float* qkv_b  = (const float*)d_in[2];
  const float* proj_w = (const float*)d_in[3];
  const float* proj_b = (const float*)d_in[4];
  const float* conv_w = (const float*)d_in[5];
  const float* conv_b = (const float*)d_in[6];

  float* out      = (float*)d_out;                      // B*N*C
  float* attn_out = out + (size_t)B_*N_*C_;             // B*H*N*N (scores then attn)
  float* u_out    = attn_out + (size_t)BHNN_;           // B*H*N*N

  // workspace layout (19.1 MB total; 28.5 MB proven safe)
  char* ws = (char*)d_ws;
  bf16* qb   = (bf16*)ws;                               // 3,145,728 B
  bf16* kb   = (bf16*)(ws + 3145728);                   // 3,145,728 B
  bf16* vTb  = (bf16*)(ws + 6291456);                   // 3,145,728 B
  float* stats = (float*)(ws + 9437184);                // 196,608 B
  unsigned long long* mbits = (unsigned long long*)(ws + 9633792); // 3,145,728 B
  float* tmp = (float*)(ws + 12779520);                 // 6,291,456 B

  // derived gumbel keys: fold_in(key(42)=(0,42), 0) and (.., 1)
  uint32_t g0k0, g0k1, g1k0, g1k1;
  { uint32_t a = 0u, b = 0u; tf2x32(0u, 42u, a, b); g0k0 = a; g0k1 = b; }
  { uint32_t a = 0u, b = 1u; tf2x32(0u, 42u, a, b); g1k0 = a; g1k1 = b; }

  dim3 blk(256);
  k_qkv   <<<dim3(64, 18),  blk, 0, stream>>>(x, qkv_w, qkv_b, qb, kb, vTb);
  k_scores<<<dim3(24576),   blk, 0, stream>>>((const short*)qb, (const short*)kb, attn_out);
  k_stats <<<dim3(24576),   blk, 0, stream>>>(attn_out, stats);
  k_fuse  <<<dim3(16384),   blk, 0, stream>>>(attn_out, stats, conv_w, conv_b,
                                              u_out, mbits,
                                              g0k0, g0k1, g1k0, g1k1);
  k_av    <<<dim3(1536),    blk, 0, stream>>>(attn_out, mbits, (const short*)vTb, tmp);
  k_proj  <<<dim3(128, 6),  blk, 0, stream>>>(tmp, proj_w, proj_b, out);
}

// Round 6
// 484.748 us; speedup vs baseline: 1.4267x; 1.1351x over previous
//
#include <hip/hip_runtime.h>
#include <hip/hip_bf16.h>
#include <stdint.h>
#include <stddef.h>

#define B_ 4
#define N_ 1024
#define C_ 384
#define H_ 6
#define D_ 64
#define TC_ 1152          // 3*C
#define BHNN_ 25165824    // B*H*N*N
#define SCALE 0.125f
#define LOG2E 1.4426950408889634f
#define LN2 0.6931471805599453f

typedef __hip_bfloat16 bf16;
typedef __attribute__((ext_vector_type(4))) float f32x4;
typedef __attribute__((ext_vector_type(8))) short short8;

__device__ __forceinline__ short f2bs(float x){
  bf16 b = __float2bfloat16(x);
  return *reinterpret_cast<short*>(&b);
}

// ---------------- Threefry-2x32 (matches jax._src.prng) ----------------
#define TFR(x0,x1,r) { x0 += x1; x1 = ((x1)<<(r))|((x1)>>(32-(r))); x1 ^= x0; }

__host__ __device__ __forceinline__ void tf2x32(uint32_t k0, uint32_t k1,
                                                uint32_t& x0, uint32_t& x1){
  uint32_t k2 = k0 ^ k1 ^ 0x1BD11BDAu;
  x0 += k0; x1 += k1;
  TFR(x0,x1,13) TFR(x0,x1,15) TFR(x0,x1,26) TFR(x0,x1,6)
  x0 += k1; x1 += k2 + 1u;
  TFR(x0,x1,17) TFR(x0,x1,29) TFR(x0,x1,16) TFR(x0,x1,24)
  x0 += k2; x1 += k0 + 2u;
  TFR(x0,x1,13) TFR(x0,x1,15) TFR(x0,x1,26) TFR(x0,x1,6)
  x0 += k0; x1 += k1 + 3u;
  TFR(x0,x1,17) TFR(x0,x1,29) TFR(x0,x1,16) TFR(x0,x1,24)
  x0 += k1; x1 += k2 + 4u;
  TFR(x0,x1,13) TFR(x0,x1,15) TFR(x0,x1,26) TFR(x0,x1,6)
  x0 += k2; x1 += k0 + 5u;
}

// partitionable threefry uniform: bits(j) = w0 ^ w1 of block(key, (0, j)); u01 in [0,1)
__device__ __forceinline__ float unif_p(uint32_t k0, uint32_t k1, uint32_t j){
  uint32_t x0 = 0u, x1 = j;
  tf2x32(k0, k1, x0, x1);
  uint32_t bits = x0 ^ x1;
  float f = __uint_as_float((bits >> 9) | 0x3F800000u) - 1.0f;
  return fmaxf(f, 1.1754943508222875e-38f);   // minval=tiny (matches JAX clamp)
}

// ---------------- Kernel A: qkv = x @ qkv_w + b -> qb, kb (B,H,N,D bf16), vT (B,H,D,N bf16)
__global__ __launch_bounds__(256) void k_qkv(const float* __restrict__ x,
                                             const float* __restrict__ w,
                                             const float* __restrict__ bias,
                                             bf16* __restrict__ qb,
                                             bf16* __restrict__ kb,
                                             bf16* __restrict__ vTb){
  __shared__ float As[16][68];   // [k][m]
  __shared__ float Bs[16][68];   // [k][n]
  const int t  = threadIdx.x;
  const int tx = t & 15, ty = t >> 4;
  const int m0 = blockIdx.x * 64, n0 = blockIdx.y * 64;
  float c[4][4] = {};
  for (int k0 = 0; k0 < C_; k0 += 16){
    #pragma unroll
    for (int i = 0; i < 4; i++){
      int idx = t + 256*i;               // 1024 A elems: 64m x 16k
      int m = idx >> 4, k = idx & 15;
      As[k][m] = x[(size_t)(m0+m)*C_ + k0 + k];
      int n = idx & 63, k2 = idx >> 6;   // 1024 B elems: 16k x 64n
      Bs[k2][n] = w[(size_t)(k0+k2)*TC_ + n0 + n];
    }
    __syncthreads();
    #pragma unroll
    for (int k = 0; k < 16; k++){
      float av[4], bv[4];
      #pragma unroll
      for (int i = 0; i < 4; i++) av[i] = As[k][ty*4+i];
      #pragma unroll
      for (int j = 0; j < 4; j++) bv[j] = Bs[k][tx*4+j];
      #pragma unroll
      for (int i = 0; i < 4; i++)
        #pragma unroll
        for (int j = 0; j < 4; j++) c[i][j] += av[i]*bv[j];
    }
    __syncthreads();
  }
  #pragma unroll
  for (int i = 0; i < 4; i++){
    int mg = m0 + ty*4 + i;
    int bb = mg >> 10, nn = mg & 1023;
    #pragma unroll
    for (int j = 0; j < 4; j++){
      int jg = n0 + tx*4 + j;
      int t3 = jg / C_;
      int rem = jg - t3*C_;
      int h = rem >> 6, d = rem & 63;
      bf16 val = __float2bfloat16(c[i][j] + bias[jg]);
      if (t3 == 0)      qb[((size_t)(bb*H_ + h)*N_ + nn)*D_ + d] = val;
      else if (t3 == 1) kb[((size_t)(bb*H_ + h)*N_ + nn)*D_ + d] = val;
      else              vTb[((size_t)(bb*H_ + h)*D_ + d)*N_ + nn] = val;
    }
  }
}

// ---------------- Kernel B (MFMA): scores[bh][n][m] = sum_d q[n,d]*k[m,d] -> f32 (attn region)
__global__ __launch_bounds__(256) void k_scores(const short* __restrict__ qb,
                                                const short* __restrict__ kb,
                                                float* __restrict__ qk){
  const int gw = blockIdx.x * 4 + (threadIdx.x >> 6);
  const int lane = threadIdx.x & 63;
  const int mt = gw & 63, nt = (gw >> 6) & 63, bh = gw >> 12;
  const int lo = lane & 15, quad = lane >> 4;
  const short* qrow = qb + ((size_t)bh*N_ + nt*16 + lo)*D_ + quad*8;
  const short* krow = kb + ((size_t)bh*N_ + mt*16 + lo)*D_ + quad*8;
  short8 a0 = *(const short8*)qrow;
  short8 b0 = *(const short8*)krow;
  short8 a1 = *(const short8*)(qrow + 32);
  short8 b1 = *(const short8*)(krow + 32);
  f32x4 acc = {0.f, 0.f, 0.f, 0.f};
  acc = __builtin_amdgcn_mfma_f32_16x16x32_bf16(a0, b0, acc, 0, 0, 0);
  acc = __builtin_amdgcn_mfma_f32_16x16x32_bf16(a1, b1, acc, 0, 0, 0);
  float* o = qk + (size_t)bh*N_*N_ + (size_t)(nt*16)*N_ + mt*16;
  #pragma unroll
  for (int r = 0; r < 4; r++)
    o[(size_t)(quad*4 + r)*N_ + lo] = acc[r];   // row=(lane>>4)*4+reg, col=lane&15
}

// ---------------- Kernel D (merged stats+softmax+conv+tanh+gumbel):
// one block per (b,n) row; handles all H=6 heads x 1024 m.
__global__ __launch_bounds__(256) void k_fuse(float* __restrict__ attn,    // in: scores, out: attn_mean
                                              const float* __restrict__ cw,
                                              const float* __restrict__ cb,
                                              float* __restrict__ u_out,
                                              unsigned long long* __restrict__ mbits,
                                              uint32_t g0k0, uint32_t g0k1,
                                              uint32_t g1k0, uint32_t g1k1){
  const int bn = blockIdx.x;                  // 0..4095
  const int bb = bn >> 10, n = bn & 1023;
  const int t = threadIdx.x, lane = t & 63, wid = t >> 6;
  __shared__ float redm[H_][4], reds[H_][4];

  float qv[H_][4];
  #pragma unroll
  for (int h = 0; h < H_; h++){
    const float* p = attn + (((size_t)(bb*H_ + h) << 10) + n) * N_;
    #pragma unroll
    for (int i = 0; i < 4; i++) qv[h][i] = p[t + 256*i];
  }
  // per-head max (wave shuffle + LDS cross-wave)
  #pragma unroll
  for (int h = 0; h < H_; h++){
    float mx = fmaxf(fmaxf(qv[h][0], qv[h][1]), fmaxf(qv[h][2], qv[h][3]));
    #pragma unroll
    for (int off = 32; off > 0; off >>= 1) mx = fmaxf(mx, __shfl_xor(mx, off));
    if (lane == 0) redm[h][wid] = mx;
  }
  __syncthreads();
  float mxh[H_], sm[H_];
  #pragma unroll
  for (int h = 0; h < H_; h++){
    mxh[h] = fmaxf(fmaxf(redm[h][0], redm[h][1]), fmaxf(redm[h][2], redm[h][3]));
    const float k2 = SCALE * LOG2E;
    float s = 0.f;
    #pragma unroll
    for (int i = 0; i < 4; i++) s += __builtin_amdgcn_exp2f((qv[h][i] - mxh[h]) * k2);
    #pragma unroll
    for (int off = 32; off > 0; off >>= 1) s += __shfl_xor(s, off);
    if (lane == 0) reds[h][wid] = s;
    sm[h] = s;
  }
  __syncthreads();
  float invS[H_];
  #pragma unroll
  for (int h = 0; h < H_; h++){
    float S = reds[h][0] + reds[h][1] + reds[h][2] + reds[h][3];
    invS[h] = __builtin_amdgcn_rcpf(S);
  }
  // write attn_mean (recompute exp)
  #pragma unroll
  for (int h = 0; h < H_; h++){
    float* p = attn + (((size_t)(bb*H_ + h) << 10) + n) * N_;
    const float k2 = SCALE * LOG2E;
    #pragma unroll
    for (int i = 0; i < 4; i++)
      p[t + 256*i] = __builtin_amdgcn_exp2f((qv[h][i] - mxh[h]) * k2) * invS[h];
  }
  // conv mix + u + gumbel hard bits
  #pragma unroll
  for (int i = 0; i < 4; i++){
    int m = t + 256*i;
    #pragma unroll
    for (int o = 0; o < H_; o++){
      float up = cb[o];
      #pragma unroll
      for (int h = 0; h < H_; h++) up += cw[o*H_ + h] * qv[h][i];
      // (tanh(up)+1)/2 == sigmoid(2*up)
      float uu = __builtin_amdgcn_rcpf(1.0f + __builtin_amdgcn_exp2f(-2.0f * up * LOG2E));
      uint32_t j = ((uint32_t)(bb*H_ + o) << 20) | ((uint32_t)n << 10) | (uint32_t)m;
      float f0 = unif_p(g0k0, g0k1, j);
      float f1 = unif_p(g1k0, g1k1, j);
      // g = -ln(-ln f) = -ln2*log2(-L) + const, const cancels in (g1-g0)
      float L0 = __builtin_amdgcn_logf(f0);      // log2, <= 0
      float L1 = __builtin_amdgcn_logf(f1);
      float d = LN2 * (__builtin_amdgcn_logf(-L0) - __builtin_amdgcn_logf(-L1));
      int hard = d > (2.0f * uu - 1.0f);
      u_out[(size_t)j] = uu;
      unsigned long long bal = __ballot(hard);
      if (lane == 0) mbits[(size_t)j >> 6] = bal;
    }
  }
}

// ---------------- Kernel E (MFMA): tmp[b,n,h,d] = sum_m (attn*mask)[bh,n,m] * v[bh,m,d]
// each wave: one 16-row n-tile x TWO 16-col d-tiles (attn read once for both)
__global__ __launch_bounds__(256) void k_av(const float* __restrict__ attn,
                                            const unsigned long long* __restrict__ mbits,
                                            const short* __restrict__ vTb,
                                            float* __restrict__ tmp){
  const int gw = blockIdx.x * 4 + (threadIdx.x >> 6);
  const int lane = threadIdx.x & 63;
  const int pr = gw & 1, nt = (gw >> 1) & 63, bh = gw >> 7;
  const int bb = bh / H_, h = bh - bb*H_;
  const int lo = lane & 15, quad = lane >> 4;
  const int row = nt*16 + lo;                       // n
  const float* arow = attn + ((size_t)bh*N_ + row)*N_ + quad*8;
  const unsigned long long* mrow = mbits + (((size_t)bh*N_ + row)*N_ >> 6);
  const short* vrow0 = vTb + ((size_t)bh*D_ + pr*32 + lo)*N_ + quad*8;
  const short* vrow1 = vrow0 + 16*N_;
  f32x4 acc0 = {0.f, 0.f, 0.f, 0.f};
  f32x4 acc1 = {0.f, 0.f, 0.f, 0.f};
  for (int m0 = 0; m0 < N_; m0 += 32){
    f32x4 av0 = *(const f32x4*)(arow + m0);
    f32x4 av1 = *(const f32x4*)(arow + m0 + 4);
    unsigned long long wb = mrow[(m0 + quad*8) >> 6];
    int base = (m0 + quad*8) & 63;
    float vals[8] = {av0[0], av0[1], av0[2], av0[3], av1[0], av1[1], av1[2], av1[3]};
    short8 a;
    #pragma unroll
    for (int j = 0; j < 8; j++)
      a[j] = f2bs(((wb >> (base + j)) & 1ull) ? vals[j] : 0.0f);
    short8 b0 = *(const short8*)(vrow0 + m0);
    short8 b1 = *(const short8*)(vrow1 + m0);
    acc0 = __builtin_amdgcn_mfma_f32_16x16x32_bf16(a, b0, acc0, 0, 0, 0);
    acc1 = __builtin_amdgcn_mfma_f32_16x16x32_bf16(a, b1, acc1, 0, 0, 0);
  }
  float* o = tmp + ((size_t)(bb*N_) + nt*16)*C_ + h*D_ + pr*32;
  #pragma unroll
  for (int r = 0; r < 4; r++){
    o[(size_t)(quad*4 + r)*C_ + lo]      = acc0[r];
    o[(size_t)(quad*4 + r)*C_ + 16 + lo] = acc1[r];
  }
}

// ---------------- Kernel F: out = tmp @ proj_w + proj_b (f32 out), 32x64 tiles
__global__ __launch_bounds__(256) void k_proj(const float* __restrict__ A,
                                              const float* __restrict__ w,
                                              const float* __restrict__ bias,
                                              float* __restrict__ out){
  __shared__ float As[16][36];   // [k][m] 32 rows
  __shared__ float Bs[16][68];   // [k][n] 64 cols
  const int t = threadIdx.x, tx = t & 15, ty = t >> 4;
  const int m0 = blockIdx.x * 32, n0 = blockIdx.y * 64;
  float c[2][4] = {};
  for (int k0 = 0; k0 < C_; k0 += 16){
    {
      int idx = t;                        // 512 A elems: 32m x 16k (2/thread)
      int m = idx >> 4, k = idx & 15;
      As[k][m] = A[(size_t)(m0+m)*C_ + k0 + k];
      idx = t + 256;
      m = idx >> 4; k = idx & 15;
      As[k][m] = A[(size_t)(m0+m)*C_ + k0 + k];
    }
    #pragma unroll
    for (int i = 0; i < 4; i++){
      int idx = t + 256*i;                // 1024 B elems: 16k x 64n
      int n = idx & 63, k2 = idx >> 6;
      Bs[k2][n] = w[(size_t)(k0+k2)*C_ + n0 + n];
    }
    __syncthreads();
    #pragma unroll
    for (int k = 0; k < 16; k++){
      float av[2], bv[4];
      #pragma unroll
      for (int i = 0; i < 2; i++) av[i] = As[k][ty*2+i];
      #pragma unroll
      for (int j = 0; j < 4; j++) bv[j] = Bs[k][tx*4+j];
      #pragma unroll
      for (int i = 0; i < 2; i++)
        #pragma unroll
        for (int j = 0; j < 4; j++) c[i][j] += av[i]*bv[j];
    }
    __syncthreads();
  }
  #pragma unroll
  for (int i = 0; i < 2; i++)
    #pragma unroll
    for (int j = 0; j < 4; j++)
      out[(size_t)(m0+ty*2+i)*C_ + n0+tx*4+j] = c[i][j] + bias[n0+tx*4+j];
}

extern "C" void kernel_launch(void* const* d_in, const int* in_sizes, int n_in,
                              void* d_out, int out_size, void* d_ws, size_t ws_size,
                              hipStream_t stream) {
  const float* x      = (const float*)d_in[0];
  const float* qkv_w  = (const float*)d_in[1];
  const float* qkv_b  = (const float*)d_in[2];
  const float* proj_w = (const float*)d_in[3];
  const float* proj_b = (const float*)d_in[4];
  const float* conv_w = (const float*)d_in[5];
  const float* conv_b = (const float*)d_in[6];

  float* out      = (float*)d_out;                      // B*N*C
  float* attn_out = out + (size_t)B_*N_*C_;             // B*H*N*N (scores then attn)
  float* u_out    = attn_out + (size_t)BHNN_;           // B*H*N*N

  // workspace layout (18.9 MB total; 28.5 MB proven safe)
  char* ws = (char*)d_ws;
  bf16* qb   = (bf16*)ws;                               // 3,145,728 B
  bf16* kb   = (bf16*)(ws + 3145728);                   // 3,145,728 B
  bf16* vTb  = (bf16*)(ws + 6291456);                   // 3,145,728 B
  unsigned long long* mbits = (unsigned long long*)(ws + 9437184); // 3,145,728 B
  float* tmp = (float*)(ws + 12582912);                 // 6,291,456 B

  // derived gumbel keys: fold_in(key(42)=(0,42), 0) and (.., 1)
  uint32_t g0k0, g0k1, g1k0, g1k1;
  { uint32_t a = 0u, b = 0u; tf2x32(0u, 42u, a, b); g0k0 = a; g0k1 = b; }
  { uint32_t a = 0u, b = 1u; tf2x32(0u, 42u, a, b); g1k0 = a; g1k1 = b; }

  dim3 blk(256);
  k_qkv   <<<dim3(64, 18),  blk, 0, stream>>>(x, qkv_w, qkv_b, qb, kb, vTb);
  k_scores<<<dim3(24576),   blk, 0, stream>>>((const short*)qb, (const short*)kb, attn_out);
  k_fuse  <<<dim3(4096),    blk, 0, stream>>>(attn_out, conv_w, conv_b,
                                              u_out, mbits,
                                              g0k0, g0k1, g1k0, g1k1);
  k_av    <<<dim3(768),     blk, 0, stream>>>(attn_out, mbits, (const short*)vTb, tmp);
  k_proj  <<<dim3(128, 6),  blk, 0, stream>>>(tmp, proj_w, proj_b, out);
}